// Round 11
// baseline (116.641 us; speedup 1.0000x reference)
//
#include <hip/hip_runtime.h>
#include <hip/hip_bf16.h>

#define BATCH 2
#define SEQ   4096
#define DM    768
#define NHEAD 12
#define HDIM  64
#define WIN   256

typedef unsigned short u16;
typedef unsigned int u32;
typedef __attribute__((ext_vector_type(8))) short bf16x8;
typedef __attribute__((ext_vector_type(4))) float f32x4;
typedef __attribute__((ext_vector_type(8))) unsigned short u16x8;
typedef __attribute__((ext_vector_type(4))) unsigned short u16x4;
typedef __attribute__((ext_vector_type(2))) unsigned int u32x2;

__device__ __forceinline__ u16 f2bf(float x) {
    unsigned u = __builtin_bit_cast(unsigned, x);
    return (u16)((u + 0x7FFFu + ((u >> 16) & 1u)) >> 16);
}

// async global->LDS, 16B per lane; LDS dest must be wave-uniform base + lane*16
#define GLL16(g, l) __builtin_amdgcn_global_load_lds( \
    (const __attribute__((address_space(1))) u32*)(g), \
    (__attribute__((address_space(3))) u32*)(l), 16, 0, 0)

// ---------------------------------------------------------------------------
// prep: [blocks 0..3071] hidden fp32 -> bf16 ; [3072..4799] W -> Wt[mat][n][k]
// ---------------------------------------------------------------------------
__global__ __launch_bounds__(256) void prep(
    const float* __restrict__ in, u16* __restrict__ Abf,
    const float* __restrict__ Wq, const float* __restrict__ Wk,
    const float* __restrict__ Wv, u16* __restrict__ Wt)
{
    __shared__ float tile[32][33];
    const int bid = blockIdx.x;
    if (bid < 3072) {
        size_t i = ((size_t)bid * 256 + threadIdx.x) * 8;
        float4 a = *(const float4*)(in + i);
        float4 b = *(const float4*)(in + i + 4);
        u16x8 r;
        r[0] = f2bf(a.x); r[1] = f2bf(a.y); r[2] = f2bf(a.z); r[3] = f2bf(a.w);
        r[4] = f2bf(b.x); r[5] = f2bf(b.y); r[6] = f2bf(b.z); r[7] = f2bf(b.w);
        *(u16x8*)(Abf + i) = r;
    } else {
        const int wb = bid - 3072;
        const int mat = wb / 576;
        const int rem = wb - mat * 576;
        const int k0 = (rem / 24) * 32, n0 = (rem % 24) * 32;
        const float* W = (mat == 0) ? Wq : (mat == 1) ? Wk : Wv;
        const int tx = threadIdx.x & 31, ty = threadIdx.x >> 5;
        #pragma unroll
        for (int i = 0; i < 32; i += 8)
            tile[ty + i][tx] = W[(size_t)(k0 + ty + i) * DM + n0 + tx];
        __syncthreads();
        #pragma unroll
        for (int i = 0; i < 32; i += 8)
            Wt[(size_t)mat * DM * DM + (size_t)(n0 + ty + i) * DM + k0 + tx] = f2bf(tile[tx][ty + i]);
    }
}

// ---------------------------------------------------------------------------
// Fused QKV GEMM (R9-proven): 128x128 tile, BK=32, 2-buffer (32KB LDS) GLL16
// pipeline, counted vmcnt(4), stage(it+2) after compute(it). Row-pair
// chunk-XOR LDS swizzle. q scaled by (1/8)*log2(e) so attn uses exp2.
// ---------------------------------------------------------------------------
__global__ __launch_bounds__(256) void qkv_mfma(
    const u16* __restrict__ Abf, const u16* __restrict__ Wt,
    const float* __restrict__ bq, const float* __restrict__ bk, const float* __restrict__ bv,
    u16* __restrict__ qo, u16* __restrict__ ko, u16* __restrict__ vT)
{
    __shared__ u16 lds[2 * 8192];   // 2 x (A 8KB + B 8KB) = 32KB

    const int t  = threadIdx.x;
    const int wv = t >> 6, ln = t & 63, lg = ln >> 4, lm = ln & 15;
    const int wr = wv >> 1, wc = wv & 1;

    // XCD-chunked swizzle: 1152 blocks, XCD c gets row-stripes [c*8, c*8+8)
    const int id  = blockIdx.x + 18 * blockIdx.y;
    const int nid = (id & 7) * 144 + (id >> 3);
    const int bx  = nid % 18, by = nid / 18;

    const int rowStart = by * 128;
    const int nG = bx * 128;
    const int mat = nG / DM;
    const int nColBase = nG - mat * DM;
    const float* bias = (mat == 0) ? bq : (mat == 1) ? bk : bv;
    const u16* Wm = Wt + (size_t)mat * DM * DM;

    f32x4 acc[4][4];
    #pragma unroll
    for (int i = 0; i < 4; i++)
        #pragma unroll
        for (int j = 0; j < 4; j++) acc[i][j] = (f32x4){0.f, 0.f, 0.f, 0.f};

    // staging: decode linear LDS slot -> (row, k-chunk) via inverse swizzle
    int r0, c0, r1, c1;
    {
        int byte0 = t * 16;
        int rp = byte0 >> 7, s = (byte0 >> 4) & 7, cf = s ^ (rp & 7);
        r0 = 2 * rp + (cf >> 2); c0 = cf & 3;
        int byte1 = 4096 + t * 16;
        rp = byte1 >> 7; s = (byte1 >> 4) & 7; cf = s ^ (rp & 7);
        r1 = 2 * rp + (cf >> 2); c1 = cf & 3;
    }
    const u16* gA0 = Abf + (size_t)(rowStart + r0) * DM + c0 * 8;
    const u16* gA1 = Abf + (size_t)(rowStart + r1) * DM + c1 * 8;
    const u16* gB0 = Wm  + (size_t)(nColBase + r0) * DM + c0 * 8;
    const u16* gB1 = Wm  + (size_t)(nColBase + r1) * DM + c1 * 8;

    auto STAGE = [&](int buf, int k0) {
        u16* base = lds + buf * 8192 + t * 8;
        GLL16(gA0 + k0, base);
        GLL16(gA1 + k0, base + 2048);
        GLL16(gB0 + k0, base + 4096);
        GLL16(gB1 + k0, base + 6144);
    };

    auto SWO = [&](int row, int lgc) -> int {
        return ((row >> 1) << 6) + (((((row & 1) << 2) + lgc) ^ ((row >> 1) & 7)) << 3);
    };

    auto COMPUTE = [&](int buf) {
        const u16* Ab = lds + buf * 8192;
        const u16* Bb = Ab + 4096;
        bf16x8 af[4], bfr[4];
        #pragma unroll
        for (int mi = 0; mi < 4; mi++) af[mi]  = *(const bf16x8*)(Ab + SWO(wr * 64 + mi * 16 + lm, lg));
        #pragma unroll
        for (int ni = 0; ni < 4; ni++) bfr[ni] = *(const bf16x8*)(Bb + SWO(wc * 64 + ni * 16 + lm, lg));
        __builtin_amdgcn_s_setprio(1);
        #pragma unroll
        for (int mi = 0; mi < 4; mi++)
            #pragma unroll
            for (int ni = 0; ni < 4; ni++)
                acc[mi][ni] = __builtin_amdgcn_mfma_f32_16x16x32_bf16(af[mi], bfr[ni], acc[mi][ni], 0, 0, 0);
        __builtin_amdgcn_s_setprio(0);
    };

    STAGE(0, 0);
    STAGE(1, 32);
    for (int it = 0; it < 23; ++it) {
        asm volatile("s_waitcnt vmcnt(4)" ::: "memory");   // this iter's 4 loads done
        __builtin_amdgcn_s_barrier();                      // all waves: buf ready
        COMPUTE(it & 1);
        __builtin_amdgcn_s_barrier();                      // all readers of buf done
        if (it < 22) STAGE(it & 1, (it + 2) * 32);         // overwrite safely
    }
    asm volatile("s_waitcnt vmcnt(0)" ::: "memory");
    __builtin_amdgcn_s_barrier();
    COMPUTE(1);

    // epilogue: bias, scale, scatter to head-split layout (VGPR-light)
    const int bb = rowStart >> 12;
    const int s0base = (rowStart & 4095) + wr * 64;
    const int col0 = nColBase + wc * 64;
    #pragma unroll
    for (int ni = 0; ni < 4; ni++) {
        const int col = col0 + ni * 16 + lm;
        const int h = col >> 6, d = col & 63;
        const float bsv = bias[col];
        #pragma unroll
        for (int mi = 0; mi < 4; mi++) {
            const int srow = s0base + mi * 16 + lg * 4;
            if (mat == 2) {
                u16x4 pk;
                #pragma unroll
                for (int r = 0; r < 4; r++) pk[r] = f2bf(acc[mi][ni][r] + bsv);
                *(u16x4*)(vT + ((size_t)((bb * NHEAD + h) * HDIM + d)) * SEQ + srow) = pk;
            } else {
                u16* dst = (mat == 0) ? qo : ko;
                // q: 1/8 (Longformer scale) * log2(e) (exp2 softmax)
                const float scl = (mat == 0) ? 0.18033688011112042f : 1.f;
                #pragma unroll
                for (int r = 0; r < 4; r++)
                    dst[((size_t)(bb * NHEAD + h) * SEQ + srow + r) * HDIM + d] =
                        f2bf((acc[mi][ni][r] + bsv) * scl);
            }
        }
    }
}

// ---------------------------------------------------------------------------
// MFMA flash attention v4: QBLK=128 (two 64-q halves share each K/V tile).
// Swapped-operand: QK^T = mfma(K,Q) -> S^T[key][q]; PV = mfma(V^T,P^T).
// 768 blocks -> single dispatch pass. K-frag LDS reads shared across halves.
// ---------------------------------------------------------------------------
__global__ __launch_bounds__(256) void attn_mfma(
    const u16* __restrict__ Q, const u16* __restrict__ K,
    const u16* __restrict__ vT, const float* __restrict__ amask,
    float* __restrict__ out)
{
    __shared__ u16 Ks[2][64][64];     // [key][d], chunk^=(key&7)
    __shared__ u16 Vs[2][64][64];     // [d][key], chunk^=(d&7)
    __shared__ u16 Pl[4][16][64];     // per-wave P[q][k], chunk^=(q&7)

    const int t  = threadIdx.x;
    const int wv = t >> 6, ln = t & 63, lg = ln >> 4, lm = ln & 15;
    const int lm7 = lm & 7;

    // XCD-chunked swizzle: 768 blocks; 96 per XCD
    const int id  = blockIdx.x + 32 * (blockIdx.y + 12 * blockIdx.z);
    const int nid = (id & 7) * 96 + (id >> 3);
    const int qtile = nid & 31;          // 32 q-tiles of 128
    const int hb = nid >> 5;
    const int h = hb % NHEAD, b = hb / NHEAD;

    const int qb0 = qtile * 128;
    const size_t bh = (size_t)(b * NHEAD + h);
    const size_t bS = (size_t)b * SEQ;

    // Q fragments for both halves (lane holds Q[q][d=lg*8..+8], q = lm-row)
    const int qrow0 = qb0 + wv * 16 + lm;
    const int qrow1 = qrow0 + 64;
    const bf16x8 qa00 = *(const bf16x8*)(Q + (bh * SEQ + qrow0) * HDIM + lg * 8);
    const bf16x8 qa01 = *(const bf16x8*)(Q + (bh * SEQ + qrow0) * HDIM + 32 + lg * 8);
    const bf16x8 qa10 = *(const bf16x8*)(Q + (bh * SEQ + qrow1) * HDIM + lg * 8);
    const bf16x8 qa11 = *(const bf16x8*)(Q + (bh * SEQ + qrow1) * HDIM + 32 + lg * 8);

    f32x4 po0[4], po1[4];
    #pragma unroll
    for (int i = 0; i < 4; i++) { po0[i] = (f32x4){0.f,0.f,0.f,0.f}; po1[i] = (f32x4){0.f,0.f,0.f,0.f}; }
    float mrun0 = -1e9f, lrun0 = 0.f, mrun1 = -1e9f, lrun1 = 0.f;

    // tiles: keys [qb0-256 + tt*64, +64), tt in [tlo, thi]
    const int tlo_raw = 4 - (qb0 >> 6);
    const int tlo = tlo_raw > 0 ? tlo_raw : 0;
    const int thi_raw = (SEQ + 192 - qb0) >> 6;
    const int thi = thi_raw < 9 ? thi_raw : 9;

    u16x8 kreg[2], vreg[2];

    auto load_regs = [&](int tt) {
        const int jt0 = qb0 - WIN + tt * 64;
        #pragma unroll
        for (int i = 0; i < 2; i++) {
            int cid = t + i * 256;
            int row = cid >> 3, c = cid & 7;
            kreg[i] = *(const u16x8*)(K  + (bh * SEQ + jt0 + row) * HDIM + c * 8);
            vreg[i] = *(const u16x8*)(vT + (bh * HDIM + row) * SEQ + jt0 + c * 8);
        }
    };
    auto write_lds = [&](int buf) {
        #pragma unroll
        for (int i = 0; i < 2; i++) {
            int cid = t + i * 256;
            int row = cid >> 3, c = cid & 7;
            *(u16x8*)&Ks[buf][row][(c ^ (row & 7)) * 8] = kreg[i];
            *(u16x8*)&Vs[buf][row][(c ^ (row & 7)) * 8] = vreg[i];
        }
    };

    load_regs(tlo);
    write_lds(0);
    __syncthreads();
    int cur = 0;

    for (int tt = tlo; tt <= thi; ++tt) {
        const int jt0 = qb0 - WIN + tt * 64;
        const float kmv = amask[bS + jt0 + ln];
        if (tt < thi) load_regs(tt + 1);

        // ---- S^T = K . Q^T for BOTH halves (K-frags loaded once) ----
        f32x4 sv0[4], sv1[4];
        #pragma unroll
        for (int jf = 0; jf < 4; jf++) { sv0[jf] = (f32x4){0.f,0.f,0.f,0.f}; sv1[jf] = (f32x4){0.f,0.f,0.f,0.f}; }
        __builtin_amdgcn_s_setprio(1);
        #pragma unroll
        for (int jf = 0; jf < 4; jf++) {
            const u16* kr = &Ks[cur][jf * 16 + lm][0];
            bf16x8 kb0 = *(const bf16x8*)(kr + ((lg ^ lm7) << 3));
            bf16x8 kb1 = *(const bf16x8*)(kr + (((4 + lg) ^ lm7) << 3));
            sv0[jf] = __builtin_amdgcn_mfma_f32_16x16x32_bf16(kb0, qa00, sv0[jf], 0, 0, 0);
            sv0[jf] = __builtin_amdgcn_mfma_f32_16x16x32_bf16(kb1, qa01, sv0[jf], 0, 0, 0);
            sv1[jf] = __builtin_amdgcn_mfma_f32_16x16x32_bf16(kb0, qa10, sv1[jf], 0, 0, 0);
            sv1[jf] = __builtin_amdgcn_mfma_f32_16x16x32_bf16(kb1, qa11, sv1[jf], 0, 0, 0);
        }
        __builtin_amdgcn_s_setprio(0);

        const bool anym = (__ballot(kmv < 0.f) != 0ULL);

        // ================= process one half =================
        auto half = [&](f32x4* sv, f32x4* po, float& mrun, float& lrun,
                        int qrow, bool fastp) {
            if (!fastp) {
                #pragma unroll
                for (int jf = 0; jf < 4; jf++)
                    #pragma unroll
                    for (int r = 0; r < 4; r++) {
                        const int j = jt0 + jf * 16 + lg * 4 + r;
                        const float km = __shfl(kmv, jf * 16 + lg * 4 + r);
                        const int rel = j - qrow;
                        const bool ok = (rel <= WIN) && (rel >= -WIN) && (km >= 0.f);
                        sv[jf][r] = ok ? sv[jf][r] : -1e9f;
                    }
            }

            f32x4 mv = sv[0];
            #pragma unroll
            for (int jf = 1; jf < 4; jf++) {
                mv[0] = fmaxf(mv[0], sv[jf][0]); mv[1] = fmaxf(mv[1], sv[jf][1]);
                mv[2] = fmaxf(mv[2], sv[jf][2]); mv[3] = fmaxf(mv[3], sv[jf][3]);
            }
            float mx = fmaxf(fmaxf(mv[0], mv[1]), fmaxf(mv[2], mv[3]));
            mx = fmaxf(mx, __shfl_xor(mx, 16));
            mx = fmaxf(mx, __shfl_xor(mx, 32));
            const float mnew = fmaxf(mrun, mx);
            const float f = exp2f(mrun - mnew);
            mrun = mnew;

            float p[4][4];
            if (fastp) {
                #pragma unroll
                for (int jf = 0; jf < 4; jf++)
                    #pragma unroll
                    for (int r = 0; r < 4; r++) p[jf][r] = exp2f(sv[jf][r] - mnew);
            } else {
                #pragma unroll
                for (int jf = 0; jf < 4; jf++)
                    #pragma unroll
                    for (int r = 0; r < 4; r++)
                        p[jf][r] = sv[jf][r] > -1e8f ? exp2f(sv[jf][r] - mnew) : 0.f;
            }

            float ps = 0.f;
            #pragma unroll
            for (int jf = 0; jf < 4; jf++)
                ps += (p[jf][0] + p[jf][1]) + (p[jf][2] + p[jf][3]);
            ps += __shfl_xor(ps, 16);
            ps += __shfl_xor(ps, 32);
            lrun = lrun * f + ps;

            // pack P -> per-wave LDS (reused by both halves sequentially)
            u32* prow = (u32*)&Pl[wv][lm][0];
            #pragma unroll
            for (int jf = 0; jf < 4; jf++) {
                u32 lo, hi;
                asm("v_cvt_pk_bf16_f32 %0, %1, %2" : "=v"(lo) : "v"(p[jf][0]), "v"(p[jf][1]));
                asm("v_cvt_pk_bf16_f32 %0, %1, %2" : "=v"(hi) : "v"(p[jf][2]), "v"(p[jf][3]));
                const int c = 2 * jf + (lg >> 1);
                u32x2 val; val[0] = lo; val[1] = hi;
                *(u32x2*)(prow + ((c ^ lm7) << 2) + ((lg & 1) << 1)) = val;
            }
            asm volatile("" ::: "memory");   // P writes before P reads (same wave)

            po[0] *= f; po[1] *= f; po[2] *= f; po[3] *= f;

            const u16* pw = &Pl[wv][lm][0];
            const bf16x8 pa0 = *(const bf16x8*)(pw + ((lg ^ lm7) << 3));
            const bf16x8 pa1 = *(const bf16x8*)(pw + (((4 + lg) ^ lm7) << 3));
            __builtin_amdgcn_s_setprio(1);
            #pragma unroll
            for (int df = 0; df < 4; df++) {
                const u16* vr = &Vs[cur][df * 16 + lm][0];
                bf16x8 va0 = *(const bf16x8*)(vr + ((lg ^ lm7) << 3));
                bf16x8 va1 = *(const bf16x8*)(vr + (((4 + lg) ^ lm7) << 3));
                po[df] = __builtin_amdgcn_mfma_f32_16x16x32_bf16(va0, pa0, po[df], 0, 0, 0);
                po[df] = __builtin_amdgcn_mfma_f32_16x16x32_bf16(va1, pa1, po[df], 0, 0, 0);
            }
            __builtin_amdgcn_s_setprio(0);
            asm volatile("" ::: "memory");   // half0's P reads before half1's writes
        };

        const bool fast0 = (tt >= 1) && (tt <= 7) && !anym;
        const bool fast1 = (tt >= 2) && (tt <= 8) && !anym;
        half(sv0, po0, mrun0, lrun0, qrow0, fast0);
        half(sv1, po1, mrun1, lrun1, qrow1, fast1);

        if (tt < thi) write_lds(cur ^ 1);
        __syncthreads();
        cur ^= 1;
    }

    // ---- epilogue: both halves ----
    {
        const float qm = amask[bS + qrow0];
        const float inv = (lrun0 > 0.f && qm >= 0.f) ? 1.f / lrun0 : 0.f;
        float* op = out + (bS + qrow0) * DM + h * HDIM;
        #pragma unroll
        for (int df = 0; df < 4; df++) {
            f32x4 o = po0[df] * inv;
            *(f32x4*)(op + df * 16 + lg * 4) = o;
        }
    }
    {
        const float qm = amask[bS + qrow1];
        const float inv = (lrun1 > 0.f && qm >= 0.f) ? 1.f / lrun1 : 0.f;
        float* op = out + (bS + qrow1) * DM + h * HDIM;
        #pragma unroll
        for (int df = 0; df < 4; df++) {
            f32x4 o = po1[df] * inv;
            *(f32x4*)(op + df * 16 + lg * 4) = o;
        }
    }
}

extern "C" void kernel_launch(void* const* d_in, const int* in_sizes, int n_in,
                              void* d_out, int out_size, void* d_ws, size_t ws_size,
                              hipStream_t stream) {
    const float* hs    = (const float*)d_in[0];
    const float* amask = (const float*)d_in[1];
    const float* Wq    = (const float*)d_in[2];
    const float* bq    = (const float*)d_in[3];
    const float* Wk    = (const float*)d_in[4];
    const float* bk    = (const float*)d_in[5];
    const float* Wv    = (const float*)d_in[6];
    const float* bv    = (const float*)d_in[7];

    const size_t nA   = (size_t)BATCH * SEQ * DM;
    const size_t nW   = (size_t)3 * DM * DM;
    const size_t nQKV = (size_t)BATCH * NHEAD * SEQ * HDIM;

    u16* Abf = (u16*)d_ws;
    u16* Wt  = Abf + nA;
    u16* qb  = Wt + nW;
    u16* kb  = qb + nQKV;
    u16* vT  = kb + nQKV;

    prep<<<4800, 256, 0, stream>>>(hs, Abf, Wq, Wk, Wv, Wt);
    qkv_mfma<<<dim3(18, 64), 256, 0, stream>>>(
        Abf, Wt, bq, bk, bv, qb, kb, vT);
    attn_mfma<<<dim3(SEQ / 128, NHEAD, BATCH), 256, 0, stream>>>(
        qb, kb, vT, amask, (float*)d_out);
}

// Round 12
// 98.085 us; speedup vs baseline: 1.1892x; 1.1892x over previous
//
#include <hip/hip_runtime.h>
#include <hip/hip_bf16.h>

#define BATCH 2
#define SEQ   4096
#define DM    768
#define NHEAD 12
#define HDIM  64
#define WIN   256

typedef unsigned short u16;
typedef unsigned int u32;
typedef __attribute__((ext_vector_type(8))) short bf16x8;
typedef __attribute__((ext_vector_type(4))) float f32x4;
typedef __attribute__((ext_vector_type(8))) unsigned short u16x8;
typedef __attribute__((ext_vector_type(4))) unsigned short u16x4;
typedef __attribute__((ext_vector_type(2))) unsigned int u32x2;
typedef __attribute__((ext_vector_type(4))) unsigned int u32x4;

__device__ __forceinline__ u16 f2bf(float x) {
    unsigned u = __builtin_bit_cast(unsigned, x);
    return (u16)((u + 0x7FFFu + ((u >> 16) & 1u)) >> 16);
}

// async global->LDS, 16B per lane; LDS dest must be wave-uniform base + lane*16
#define GLL16(g, l) __builtin_amdgcn_global_load_lds( \
    (const __attribute__((address_space(1))) u32*)(g), \
    (__attribute__((address_space(3))) u32*)(l), 16, 0, 0)

// ---------------------------------------------------------------------------
// prep (wtrans only now): W[k][n] fp32 -> Wt[mat][n][k] bf16. 1728 blocks.
// ---------------------------------------------------------------------------
__global__ __launch_bounds__(256) void prep(
    const float* __restrict__ Wq, const float* __restrict__ Wk,
    const float* __restrict__ Wv, u16* __restrict__ Wt)
{
    __shared__ float tile[32][33];
    const int bid = blockIdx.x;
    const int mat = bid / 576;
    const int rem = bid - mat * 576;
    const int k0 = (rem / 24) * 32, n0 = (rem % 24) * 32;
    const float* W = (mat == 0) ? Wq : (mat == 1) ? Wk : Wv;
    const int tx = threadIdx.x & 31, ty = threadIdx.x >> 5;
    #pragma unroll
    for (int i = 0; i < 32; i += 8)
        tile[ty + i][tx] = W[(size_t)(k0 + ty + i) * DM + n0 + tx];
    __syncthreads();
    #pragma unroll
    for (int i = 0; i < 32; i += 8)
        Wt[(size_t)mat * DM * DM + (size_t)(n0 + ty + i) * DM + k0 + tx] = f2bf(tile[tx][ty + i]);
}

// ---------------------------------------------------------------------------
// Fused QKV GEMM v6: 128x128 tile, BK=32, 2-buffer counted-vmcnt(6) pipeline.
// A staged as RAW FP32 (no aconv pass) and converted to bf16 in-register via
// v_cvt_pk_bf16_f32 after ds_read_b128 x2 (identical RNE rounding to f2bf).
// A region (16KB/buf, 128B rows): slot = chunk ^ (row&7) swizzle.
// B region (8KB/buf, bf16 64B rows): row-pair chunk-XOR swizzle (R9-proven).
// Inverse swizzle applied to per-lane GLOBAL source; LDS dest linear.
// q scaled by (1/8)*log2(e) so attn uses exp2.
// ---------------------------------------------------------------------------
__global__ __launch_bounds__(256) void qkv_mfma(
    const float* __restrict__ A, const u16* __restrict__ Wt,
    const float* __restrict__ bq, const float* __restrict__ bk, const float* __restrict__ bv,
    u16* __restrict__ qo, u16* __restrict__ ko, u16* __restrict__ vT)
{
    __shared__ u16 lds[2 * 12288];   // 2 x (A-fp32 16KB + B-bf16 8KB) = 48KB

    const int t  = threadIdx.x;
    const int wv = t >> 6, ln = t & 63, lg = ln >> 4, lm = ln & 15;
    const int wr = wv >> 1, wc = wv & 1;

    // XCD-chunked swizzle: 1152 blocks, XCD c gets row-stripes [c*8, c*8+8)
    const int id  = blockIdx.x + 18 * blockIdx.y;
    const int nid = (id & 7) * 144 + (id >> 3);
    const int bx  = nid % 18, by = nid / 18;

    const int rowStart = by * 128;
    const int nG = bx * 128;
    const int mat = nG / DM;
    const int nColBase = nG - mat * DM;
    const float* bias = (mat == 0) ? bq : (mat == 1) ? bk : bv;
    const u16* Wm = Wt + (size_t)mat * DM * DM;

    f32x4 acc[4][4];
    #pragma unroll
    for (int i = 0; i < 4; i++)
        #pragma unroll
        for (int j = 0; j < 4; j++) acc[i][j] = (f32x4){0.f, 0.f, 0.f, 0.f};

    // ---- A staging decode (per 4KB call-line ci): LDS byte = ci*4096 + t*16
    //      row = ci*32 + (t>>3); stored slot = t&7; global chunk = slot^(row&7)
    const int rA  = t >> 3;                       // 0..31 (row within call-line)
    const int chA = (t & 7) ^ (rA & 7);           // inverse swizzle (ci*32 = 0 mod 8)
    const float* gA0 = A + (size_t)(rowStart +  0 + rA) * DM + chA * 4;
    const float* gA1 = A + (size_t)(rowStart + 32 + rA) * DM + chA * 4;
    const float* gA2 = A + (size_t)(rowStart + 64 + rA) * DM + chA * 4;
    const float* gA3 = A + (size_t)(rowStart + 96 + rA) * DM + chA * 4;

    // ---- B staging decode (row-pair swizzle, 64B bf16 rows):
    //      LDS byte = cj*4096 + t*16; rp = cj*32 + (t>>3); slot = t&7;
    //      cfull = slot^(rp&7); row = 2*rp + (cfull>>2); col = (cfull&3)*8
    const int cfB = (t & 7) ^ (rA & 7);
    const int rB  = 2 * rA + (cfB >> 2);
    const int cB  = (cfB & 3) * 8;
    const u16* gB0 = Wm + (size_t)(nColBase +  0 + rB) * DM + cB;
    const u16* gB1 = Wm + (size_t)(nColBase + 64 + rB) * DM + cB;

    auto STAGE = [&](int buf, int k0) {
        u16* base = lds + buf * 12288 + t * 8;
        GLL16(gA0 + k0, base);             // A bytes [0,4K)
        GLL16(gA1 + k0, base + 2048);      // [4K,8K)
        GLL16(gA2 + k0, base + 4096);      // [8K,12K)
        GLL16(gA3 + k0, base + 6144);      // [12K,16K)
        GLL16(gB0 + k0, base + 8192);      // B [16K,20K)
        GLL16(gB1 + k0, base + 10240);     // B [20K,24K)
    };

    // B read offset (u16 units) for (row, chunk lgc), row-pair swizzle
    auto SWOB = [&](int row, int lgc) -> int {
        return ((row >> 1) << 6) + (((((row & 1) << 2) + lgc) ^ ((row >> 1) & 7)) << 3);
    };

    auto COMPUTE = [&](int buf) {
        const float* Af = (const float*)(lds + buf * 12288);
        const u16*  Bb  = lds + buf * 12288 + 8192;
        bf16x8 af[4], bfr[4];
        #pragma unroll
        for (int mi = 0; mi < 4; mi++) {
            const int r = wr * 64 + mi * 16 + lm;
            const float* rowp = Af + r * 32;
            f32x4 a0 = *(const f32x4*)(rowp + ((( 2 * lg)     ^ (r & 7)) << 2));
            f32x4 a1 = *(const f32x4*)(rowp + (((2 * lg + 1)  ^ (r & 7)) << 2));
            u32x4 w;
            asm("v_cvt_pk_bf16_f32 %0, %1, %2" : "=v"(w[0]) : "v"(a0[0]), "v"(a0[1]));
            asm("v_cvt_pk_bf16_f32 %0, %1, %2" : "=v"(w[1]) : "v"(a0[2]), "v"(a0[3]));
            asm("v_cvt_pk_bf16_f32 %0, %1, %2" : "=v"(w[2]) : "v"(a1[0]), "v"(a1[1]));
            asm("v_cvt_pk_bf16_f32 %0, %1, %2" : "=v"(w[3]) : "v"(a1[2]), "v"(a1[3]));
            af[mi] = __builtin_bit_cast(bf16x8, w);
        }
        #pragma unroll
        for (int ni = 0; ni < 4; ni++)
            bfr[ni] = *(const bf16x8*)(Bb + SWOB(wc * 64 + ni * 16 + lm, lg));
        __builtin_amdgcn_s_setprio(1);
        #pragma unroll
        for (int mi = 0; mi < 4; mi++)
            #pragma unroll
            for (int ni = 0; ni < 4; ni++)
                acc[mi][ni] = __builtin_amdgcn_mfma_f32_16x16x32_bf16(af[mi], bfr[ni], acc[mi][ni], 0, 0, 0);
        __builtin_amdgcn_s_setprio(0);
    };

    STAGE(0, 0);
    STAGE(1, 32);
    for (int it = 0; it < 23; ++it) {
        asm volatile("s_waitcnt vmcnt(6)" ::: "memory");   // this iter's 6 loads done
        __builtin_amdgcn_s_barrier();                      // all waves: buf ready
        COMPUTE(it & 1);
        __builtin_amdgcn_s_barrier();                      // all readers of buf done
        if (it < 22) STAGE(it & 1, (it + 2) * 32);         // overwrite safely
    }
    asm volatile("s_waitcnt vmcnt(0)" ::: "memory");
    __builtin_amdgcn_s_barrier();
    COMPUTE(1);

    // epilogue: bias, scale, scatter to head-split layout (VGPR-light, R9)
    const int bb = rowStart >> 12;
    const int s0base = (rowStart & 4095) + wr * 64;
    const int col0 = nColBase + wc * 64;
    #pragma unroll
    for (int ni = 0; ni < 4; ni++) {
        const int col = col0 + ni * 16 + lm;
        const int h = col >> 6, d = col & 63;
        const float bsv = bias[col];
        #pragma unroll
        for (int mi = 0; mi < 4; mi++) {
            const int srow = s0base + mi * 16 + lg * 4;
            if (mat == 2) {
                u16x4 pk;
                #pragma unroll
                for (int r = 0; r < 4; r++) pk[r] = f2bf(acc[mi][ni][r] + bsv);
                *(u16x4*)(vT + ((size_t)((bb * NHEAD + h) * HDIM + d)) * SEQ + srow) = pk;
            } else {
                u16* dst = (mat == 0) ? qo : ko;
                // q: 1/8 (Longformer scale) * log2(e) (exp2 softmax)
                const float scl = (mat == 0) ? 0.18033688011112042f : 1.f;
                #pragma unroll
                for (int r = 0; r < 4; r++)
                    dst[((size_t)(bb * NHEAD + h) * SEQ + srow + r) * HDIM + d] =
                        f2bf((acc[mi][ni][r] + bsv) * scl);
            }
        }
    }
}

// ---------------------------------------------------------------------------
// MFMA flash attention, swapped-operand form (R6/R9-proven).
// QK^T: mfma(K,Q) -> S^T[key][q]; each thread owns q=lm (scalar m,l).
// PV:   mfma(V^T,P^T) -> O^T[d][q]; rescale factor is thread-scalar.
// LDS = 40KB exactly -> 4 blocks/CU. XCD-chunked swizzle for K/V L2 reuse.
// ---------------------------------------------------------------------------
__global__ __launch_bounds__(256, 4) void attn_mfma(
    const u16* __restrict__ Q, const u16* __restrict__ K,
    const u16* __restrict__ vT, const float* __restrict__ amask,
    float* __restrict__ out)
{
    __shared__ u16 Ks[2][64][64];     // [key][d], chunk^=(key&7)
    __shared__ u16 Vs[2][64][64];     // [d][key], chunk^=(d&7)
    __shared__ u16 Pl[4][16][64];     // per-wave P[q][k], chunk^=(q&7)

    const int t  = threadIdx.x;
    const int wv = t >> 6, ln = t & 63, lg = ln >> 4, lm = ln & 15;
    const int lm7 = lm & 7;

    // XCD-chunked swizzle: 1536 blocks; XCD c gets 3 full (b,h) panels
    const int id  = blockIdx.x + 64 * (blockIdx.y + 12 * blockIdx.z);
    const int nid = (id & 7) * 192 + (id >> 3);
    const int qtile = nid & 63;
    const int hb = nid >> 6;
    const int h = hb % NHEAD, b = hb / NHEAD;

    const int qb0 = qtile * 64;
    const size_t bh = (size_t)(b * NHEAD + h);
    const size_t bS = (size_t)b * SEQ;

    const int qrow = qb0 + wv * 16 + lm;
    const bf16x8 qa0 = *(const bf16x8*)(Q + (bh * SEQ + qrow) * HDIM + lg * 8);
    const bf16x8 qa1 = *(const bf16x8*)(Q + (bh * SEQ + qrow) * HDIM + 32 + lg * 8);

    f32x4 po[4];
    #pragma unroll
    for (int i = 0; i < 4; i++) po[i] = (f32x4){0.f, 0.f, 0.f, 0.f};
    float mrun = -1e9f, lrun = 0.f;

    const int tlo = (4 - qtile) > 0 ? (4 - qtile) : 0;
    const int thi_raw = (SEQ + 192 - qb0) >> 6;
    const int thi = thi_raw < 8 ? thi_raw : 8;

    u16x8 kreg[2], vreg[2];

    auto load_regs = [&](int tt) {
        const int jt0 = qb0 - WIN + tt * 64;
        #pragma unroll
        for (int i = 0; i < 2; i++) {
            int cid = t + i * 256;
            int row = cid >> 3, c = cid & 7;
            kreg[i] = *(const u16x8*)(K  + (bh * SEQ + jt0 + row) * HDIM + c * 8);
            vreg[i] = *(const u16x8*)(vT + (bh * HDIM + row) * SEQ + jt0 + c * 8);
        }
    };
    auto write_lds = [&](int buf) {
        #pragma unroll
        for (int i = 0; i < 2; i++) {
            int cid = t + i * 256;
            int row = cid >> 3, c = cid & 7;
            *(u16x8*)&Ks[buf][row][(c ^ (row & 7)) * 8] = kreg[i];
            *(u16x8*)&Vs[buf][row][(c ^ (row & 7)) * 8] = vreg[i];
        }
    };

    load_regs(tlo);
    write_lds(0);
    __syncthreads();
    int cur = 0;

    for (int tt = tlo; tt <= thi; ++tt) {
        const int jt0 = qb0 - WIN + tt * 64;
        const float kmv = amask[bS + jt0 + ln];
        if (tt < thi) load_regs(tt + 1);

        // ---- S^T = K . Q^T ----
        f32x4 sv[4];
        #pragma unroll
        for (int jf = 0; jf < 4; jf++) sv[jf] = (f32x4){0.f, 0.f, 0.f, 0.f};
        __builtin_amdgcn_s_setprio(1);
        #pragma unroll
        for (int jf = 0; jf < 4; jf++) {
            const u16* kr = &Ks[cur][jf * 16 + lm][0];
            bf16x8 kb0 = *(const bf16x8*)(kr + ((lg ^ lm7) << 3));
            bf16x8 kb1 = *(const bf16x8*)(kr + (((4 + lg) ^ lm7) << 3));
            sv[jf] = __builtin_amdgcn_mfma_f32_16x16x32_bf16(kb0, qa0, sv[jf], 0, 0, 0);
            sv[jf] = __builtin_amdgcn_mfma_f32_16x16x32_bf16(kb1, qa1, sv[jf], 0, 0, 0);
        }
        __builtin_amdgcn_s_setprio(0);

        const bool anym = (__ballot(kmv < 0.f) != 0ULL);
        const bool fastp = (tt >= 1) && (tt <= 7) && !anym;
        if (!fastp) {
            #pragma unroll
            for (int jf = 0; jf < 4; jf++)
                #pragma unroll
                for (int r = 0; r < 4; r++) {
                    const int j = jt0 + jf * 16 + lg * 4 + r;
                    const float km = __shfl(kmv, jf * 16 + lg * 4 + r);
                    const int rel = j - qrow;
                    const bool ok = (rel <= WIN) && (rel >= -WIN) && (km >= 0.f);
                    sv[jf][r] = ok ? sv[jf][r] : -1e9f;
                }
        }

        // ---- online softmax: thread-scalar m,l for q=lm ----
        f32x4 mv = sv[0];
        #pragma unroll
        for (int jf = 1; jf < 4; jf++) {
            mv[0] = fmaxf(mv[0], sv[jf][0]); mv[1] = fmaxf(mv[1], sv[jf][1]);
            mv[2] = fmaxf(mv[2], sv[jf][2]); mv[3] = fmaxf(mv[3], sv[jf][3]);
        }
        float mx = fmaxf(fmaxf(mv[0], mv[1]), fmaxf(mv[2], mv[3]));
        mx = fmaxf(mx, __shfl_xor(mx, 16));
        mx = fmaxf(mx, __shfl_xor(mx, 32));
        const float mnew = fmaxf(mrun, mx);
        const float f = exp2f(mrun - mnew);
        mrun = mnew;

        float p[4][4];
        if (fastp) {
            #pragma unroll
            for (int jf = 0; jf < 4; jf++)
                #pragma unroll
                for (int r = 0; r < 4; r++) p[jf][r] = exp2f(sv[jf][r] - mnew);
        } else {
            #pragma unroll
            for (int jf = 0; jf < 4; jf++)
                #pragma unroll
                for (int r = 0; r < 4; r++)
                    p[jf][r] = sv[jf][r] > -1e8f ? exp2f(sv[jf][r] - mnew) : 0.f;
        }

        float ps = 0.f;
        #pragma unroll
        for (int jf = 0; jf < 4; jf++)
            ps += (p[jf][0] + p[jf][1]) + (p[jf][2] + p[jf][3]);
        ps += __shfl_xor(ps, 16);
        ps += __shfl_xor(ps, 32);
        lrun = lrun * f + ps;

        // ---- pack P -> LDS ----
        u32* prow = (u32*)&Pl[wv][lm][0];
        #pragma unroll
        for (int jf = 0; jf < 4; jf++) {
            u32 lo, hi;
            asm("v_cvt_pk_bf16_f32 %0, %1, %2" : "=v"(lo) : "v"(p[jf][0]), "v"(p[jf][1]));
            asm("v_cvt_pk_bf16_f32 %0, %1, %2" : "=v"(hi) : "v"(p[jf][2]), "v"(p[jf][3]));
            const int c = 2 * jf + (lg >> 1);
            u32x2 val; val[0] = lo; val[1] = hi;
            *(u32x2*)(prow + ((c ^ lm7) << 2) + ((lg & 1) << 1)) = val;
        }
        asm volatile("" ::: "memory");

        po[0] *= f; po[1] *= f; po[2] *= f; po[3] *= f;

        // ---- O^T += V^T . P^T ----
        const u16* pw = &Pl[wv][lm][0];
        const bf16x8 pa0 = *(const bf16x8*)(pw + ((lg ^ lm7) << 3));
        const bf16x8 pa1 = *(const bf16x8*)(pw + (((4 + lg) ^ lm7) << 3));
        __builtin_amdgcn_s_setprio(1);
        #pragma unroll
        for (int df = 0; df < 4; df++) {
            const u16* vr = &Vs[cur][df * 16 + lm][0];
            bf16x8 va0 = *(const bf16x8*)(vr + ((lg ^ lm7) << 3));
            bf16x8 va1 = *(const bf16x8*)(vr + (((4 + lg) ^ lm7) << 3));
            po[df] = __builtin_amdgcn_mfma_f32_16x16x32_bf16(va0, pa0, po[df], 0, 0, 0);
            po[df] = __builtin_amdgcn_mfma_f32_16x16x32_bf16(va1, pa1, po[df], 0, 0, 0);
        }
        __builtin_amdgcn_s_setprio(0);

        if (tt < thi) write_lds(cur ^ 1);
        __syncthreads();
        cur ^= 1;
    }

    const float qm = amask[bS + qrow];
    const float inv = (lrun > 0.f && qm >= 0.f) ? 1.f / lrun : 0.f;
    float* op = out + (bS + qrow) * DM + h * HDIM;
    #pragma unroll
    for (int df = 0; df < 4; df++) {
        f32x4 o = po[df] * inv;
        *(f32x4*)(op + df * 16 + lg * 4) = o;
    }
}

extern "C" void kernel_launch(void* const* d_in, const int* in_sizes, int n_in,
                              void* d_out, int out_size, void* d_ws, size_t ws_size,
                              hipStream_t stream) {
    const float* hs    = (const float*)d_in[0];
    const float* amask = (const float*)d_in[1];
    const float* Wq    = (const float*)d_in[2];
    const float* bq    = (const float*)d_in[3];
    const float* Wk    = (const float*)d_in[4];
    const float* bk    = (const float*)d_in[5];
    const float* Wv    = (const float*)d_in[6];
    const float* bv    = (const float*)d_in[7];

    const size_t nW   = (size_t)3 * DM * DM;
    const size_t nQKV = (size_t)BATCH * NHEAD * SEQ * HDIM;

    u16* Wt = (u16*)d_ws;
    u16* qb = Wt + nW;
    u16* kb = qb + nQKV;
    u16* vT = kb + nQKV;

    prep<<<1728, 256, 0, stream>>>(Wq, Wk, Wv, Wt);
    qkv_mfma<<<dim3(18, 64), 256, 0, stream>>>(
        hs, Wt, bq, bk, bv, qb, kb, vT);
    attn_mfma<<<dim3(SEQ / 64, NHEAD, BATCH), 256, 0, stream>>>(
        qb, kb, vT, amask, (float*)d_out);
}

// Round 13
// 93.866 us; speedup vs baseline: 1.2426x; 1.0449x over previous
//
#include <hip/hip_runtime.h>
#include <hip/hip_bf16.h>

#define BATCH 2
#define SEQ   4096
#define DM    768
#define NHEAD 12
#define HDIM  64
#define WIN   256

typedef unsigned short u16;
typedef unsigned int u32;
typedef __attribute__((ext_vector_type(8))) short bf16x8;
typedef __attribute__((ext_vector_type(4))) float f32x4;
typedef __attribute__((ext_vector_type(8))) unsigned short u16x8;
typedef __attribute__((ext_vector_type(4))) unsigned short u16x4;
typedef __attribute__((ext_vector_type(2))) unsigned int u32x2;

__device__ __forceinline__ u16 f2bf(float x) {
    unsigned u = __builtin_bit_cast(unsigned, x);
    return (u16)((u + 0x7FFFu + ((u >> 16) & 1u)) >> 16);
}

// async global->LDS, 16B per lane; LDS dest must be wave-uniform base + lane*16
#define GLL16(g, l) __builtin_amdgcn_global_load_lds( \
    (const __attribute__((address_space(1))) u32*)(g), \
    (__attribute__((address_space(3))) u32*)(l), 16, 0, 0)

// ---------------------------------------------------------------------------
// prep: [blocks 0..3071] hidden fp32 -> bf16 ; [3072..4799] W -> Wt[mat][n][k]
// ---------------------------------------------------------------------------
__global__ __launch_bounds__(256) void prep(
    const float* __restrict__ in, u16* __restrict__ Abf,
    const float* __restrict__ Wq, const float* __restrict__ Wk,
    const float* __restrict__ Wv, u16* __restrict__ Wt)
{
    __shared__ float tile[32][33];
    const int bid = blockIdx.x;
    if (bid < 3072) {
        size_t i = ((size_t)bid * 256 + threadIdx.x) * 8;
        float4 a = *(const float4*)(in + i);
        float4 b = *(const float4*)(in + i + 4);
        u16x8 r;
        r[0] = f2bf(a.x); r[1] = f2bf(a.y); r[2] = f2bf(a.z); r[3] = f2bf(a.w);
        r[4] = f2bf(b.x); r[5] = f2bf(b.y); r[6] = f2bf(b.z); r[7] = f2bf(b.w);
        *(u16x8*)(Abf + i) = r;
    } else {
        const int wb = bid - 3072;
        const int mat = wb / 576;
        const int rem = wb - mat * 576;
        const int k0 = (rem / 24) * 32, n0 = (rem % 24) * 32;
        const float* W = (mat == 0) ? Wq : (mat == 1) ? Wk : Wv;
        const int tx = threadIdx.x & 31, ty = threadIdx.x >> 5;
        #pragma unroll
        for (int i = 0; i < 32; i += 8)
            tile[ty + i][tx] = W[(size_t)(k0 + ty + i) * DM + n0 + tx];
        __syncthreads();
        #pragma unroll
        for (int i = 0; i < 32; i += 8)
            Wt[(size_t)mat * DM * DM + (size_t)(n0 + ty + i) * DM + k0 + tx] = f2bf(tile[tx][ty + i]);
    }
}

// ---------------------------------------------------------------------------
// Fused QKV GEMM (R9-proven): 128x128 tile, BK=32, 2-buffer (32KB LDS) GLL16
// pipeline, counted vmcnt(4), stage(it+2) after compute(it). Row-pair
// chunk-XOR LDS swizzle. q scaled by (1/8)*log2(e) so attn uses exp2.
// ---------------------------------------------------------------------------
__global__ __launch_bounds__(256) void qkv_mfma(
    const u16* __restrict__ Abf, const u16* __restrict__ Wt,
    const float* __restrict__ bq, const float* __restrict__ bk, const float* __restrict__ bv,
    u16* __restrict__ qo, u16* __restrict__ ko, u16* __restrict__ vT)
{
    __shared__ u16 lds[2 * 8192];   // 2 x (A 8KB + B 8KB) = 32KB

    const int t  = threadIdx.x;
    const int wv = t >> 6, ln = t & 63, lg = ln >> 4, lm = ln & 15;
    const int wr = wv >> 1, wc = wv & 1;

    // XCD-chunked swizzle: 1152 blocks, XCD c gets row-stripes [c*8, c*8+8)
    const int id  = blockIdx.x + 18 * blockIdx.y;
    const int nid = (id & 7) * 144 + (id >> 3);
    const int bx  = nid % 18, by = nid / 18;

    const int rowStart = by * 128;
    const int nG = bx * 128;
    const int mat = nG / DM;
    const int nColBase = nG - mat * DM;
    const float* bias = (mat == 0) ? bq : (mat == 1) ? bk : bv;
    const u16* Wm = Wt + (size_t)mat * DM * DM;

    f32x4 acc[4][4];
    #pragma unroll
    for (int i = 0; i < 4; i++)
        #pragma unroll
        for (int j = 0; j < 4; j++) acc[i][j] = (f32x4){0.f, 0.f, 0.f, 0.f};

    // staging: decode linear LDS slot -> (row, k-chunk) via inverse swizzle
    int r0, c0, r1, c1;
    {
        int byte0 = t * 16;
        int rp = byte0 >> 7, s = (byte0 >> 4) & 7, cf = s ^ (rp & 7);
        r0 = 2 * rp + (cf >> 2); c0 = cf & 3;
        int byte1 = 4096 + t * 16;
        rp = byte1 >> 7; s = (byte1 >> 4) & 7; cf = s ^ (rp & 7);
        r1 = 2 * rp + (cf >> 2); c1 = cf & 3;
    }
    const u16* gA0 = Abf + (size_t)(rowStart + r0) * DM + c0 * 8;
    const u16* gA1 = Abf + (size_t)(rowStart + r1) * DM + c1 * 8;
    const u16* gB0 = Wm  + (size_t)(nColBase + r0) * DM + c0 * 8;
    const u16* gB1 = Wm  + (size_t)(nColBase + r1) * DM + c1 * 8;

    auto STAGE = [&](int buf, int k0) {
        u16* base = lds + buf * 8192 + t * 8;
        GLL16(gA0 + k0, base);
        GLL16(gA1 + k0, base + 2048);
        GLL16(gB0 + k0, base + 4096);
        GLL16(gB1 + k0, base + 6144);
    };

    auto SWO = [&](int row, int lgc) -> int {
        return ((row >> 1) << 6) + (((((row & 1) << 2) + lgc) ^ ((row >> 1) & 7)) << 3);
    };

    auto COMPUTE = [&](int buf) {
        const u16* Ab = lds + buf * 8192;
        const u16* Bb = Ab + 4096;
        bf16x8 af[4], bfr[4];
        #pragma unroll
        for (int mi = 0; mi < 4; mi++) af[mi]  = *(const bf16x8*)(Ab + SWO(wr * 64 + mi * 16 + lm, lg));
        #pragma unroll
        for (int ni = 0; ni < 4; ni++) bfr[ni] = *(const bf16x8*)(Bb + SWO(wc * 64 + ni * 16 + lm, lg));
        __builtin_amdgcn_s_setprio(1);
        #pragma unroll
        for (int mi = 0; mi < 4; mi++)
            #pragma unroll
            for (int ni = 0; ni < 4; ni++)
                acc[mi][ni] = __builtin_amdgcn_mfma_f32_16x16x32_bf16(af[mi], bfr[ni], acc[mi][ni], 0, 0, 0);
        __builtin_amdgcn_s_setprio(0);
    };

    STAGE(0, 0);
    STAGE(1, 32);
    for (int it = 0; it < 23; ++it) {
        asm volatile("s_waitcnt vmcnt(4)" ::: "memory");   // this iter's 4 loads done
        __builtin_amdgcn_s_barrier();                      // all waves: buf ready
        COMPUTE(it & 1);
        __builtin_amdgcn_s_barrier();                      // all readers of buf done
        if (it < 22) STAGE(it & 1, (it + 2) * 32);         // overwrite safely
    }
    asm volatile("s_waitcnt vmcnt(0)" ::: "memory");
    __builtin_amdgcn_s_barrier();
    COMPUTE(1);

    // epilogue: bias, scale, scatter to head-split layout (VGPR-light)
    const int bb = rowStart >> 12;
    const int s0base = (rowStart & 4095) + wr * 64;
    const int col0 = nColBase + wc * 64;
    #pragma unroll
    for (int ni = 0; ni < 4; ni++) {
        const int col = col0 + ni * 16 + lm;
        const int h = col >> 6, d = col & 63;
        const float bsv = bias[col];
        #pragma unroll
        for (int mi = 0; mi < 4; mi++) {
            const int srow = s0base + mi * 16 + lg * 4;
            if (mat == 2) {
                u16x4 pk;
                #pragma unroll
                for (int r = 0; r < 4; r++) pk[r] = f2bf(acc[mi][ni][r] + bsv);
                *(u16x4*)(vT + ((size_t)((bb * NHEAD + h) * HDIM + d)) * SEQ + srow) = pk;
            } else {
                u16* dst = (mat == 0) ? qo : ko;
                // q: 1/8 (Longformer scale) * log2(e) (exp2 softmax)
                const float scl = (mat == 0) ? 0.18033688011112042f : 1.f;
                #pragma unroll
                for (int r = 0; r < 4; r++)
                    dst[((size_t)(bb * NHEAD + h) * SEQ + srow + r) * HDIM + d] =
                        f2bf((acc[mi][ni][r] + bsv) * scl);
            }
        }
    }
}

// ---------------------------------------------------------------------------
// MFMA flash attention, swapped-operand form (R6/R9-proven).
// QK^T: mfma(K,Q) -> S^T[key][q]; each thread owns q=lm (scalar m,l).
// PV:   mfma(V^T,P^T) -> O^T[d][q]; rescale factor is thread-scalar.
// LDS = 40KB exactly -> 4 blocks/CU. XCD-chunked swizzle for K/V L2 reuse.
// ---------------------------------------------------------------------------
__global__ __launch_bounds__(256, 4) void attn_mfma(
    const u16* __restrict__ Q, const u16* __restrict__ K,
    const u16* __restrict__ vT, const float* __restrict__ amask,
    float* __restrict__ out)
{
    __shared__ u16 Ks[2][64][64];     // [key][d], chunk^=(key&7)
    __shared__ u16 Vs[2][64][64];     // [d][key], chunk^=(d&7)
    __shared__ u16 Pl[4][16][64];     // per-wave P[q][k], chunk^=(q&7)

    const int t  = threadIdx.x;
    const int wv = t >> 6, ln = t & 63, lg = ln >> 4, lm = ln & 15;
    const int lm7 = lm & 7;

    // XCD-chunked swizzle: 1536 blocks; XCD c gets 3 full (b,h) panels
    const int id  = blockIdx.x + 64 * (blockIdx.y + 12 * blockIdx.z);
    const int nid = (id & 7) * 192 + (id >> 3);
    const int qtile = nid & 63;
    const int hb = nid >> 6;
    const int h = hb % NHEAD, b = hb / NHEAD;

    const int qb0 = qtile * 64;
    const size_t bh = (size_t)(b * NHEAD + h);
    const size_t bS = (size_t)b * SEQ;

    const int qrow = qb0 + wv * 16 + lm;
    const bf16x8 qa0 = *(const bf16x8*)(Q + (bh * SEQ + qrow) * HDIM + lg * 8);
    const bf16x8 qa1 = *(const bf16x8*)(Q + (bh * SEQ + qrow) * HDIM + 32 + lg * 8);

    f32x4 po[4];
    #pragma unroll
    for (int i = 0; i < 4; i++) po[i] = (f32x4){0.f, 0.f, 0.f, 0.f};
    float mrun = -1e9f, lrun = 0.f;

    const int tlo = (4 - qtile) > 0 ? (4 - qtile) : 0;
    const int thi_raw = (SEQ + 192 - qb0) >> 6;
    const int thi = thi_raw < 8 ? thi_raw : 8;

    u16x8 kreg[2], vreg[2];

    auto load_regs = [&](int tt) {
        const int jt0 = qb0 - WIN + tt * 64;
        #pragma unroll
        for (int i = 0; i < 2; i++) {
            int cid = t + i * 256;
            int row = cid >> 3, c = cid & 7;
            kreg[i] = *(const u16x8*)(K  + (bh * SEQ + jt0 + row) * HDIM + c * 8);
            vreg[i] = *(const u16x8*)(vT + (bh * HDIM + row) * SEQ + jt0 + c * 8);
        }
    };
    auto write_lds = [&](int buf) {
        #pragma unroll
        for (int i = 0; i < 2; i++) {
            int cid = t + i * 256;
            int row = cid >> 3, c = cid & 7;
            *(u16x8*)&Ks[buf][row][(c ^ (row & 7)) * 8] = kreg[i];
            *(u16x8*)&Vs[buf][row][(c ^ (row & 7)) * 8] = vreg[i];
        }
    };

    load_regs(tlo);
    write_lds(0);
    __syncthreads();
    int cur = 0;

    for (int tt = tlo; tt <= thi; ++tt) {
        const int jt0 = qb0 - WIN + tt * 64;
        const float kmv = amask[bS + jt0 + ln];
        if (tt < thi) load_regs(tt + 1);

        // ---- S^T = K . Q^T ----
        f32x4 sv[4];
        #pragma unroll
        for (int jf = 0; jf < 4; jf++) sv[jf] = (f32x4){0.f, 0.f, 0.f, 0.f};
        __builtin_amdgcn_s_setprio(1);
        #pragma unroll
        for (int jf = 0; jf < 4; jf++) {
            const u16* kr = &Ks[cur][jf * 16 + lm][0];
            bf16x8 kb0 = *(const bf16x8*)(kr + ((lg ^ lm7) << 3));
            bf16x8 kb1 = *(const bf16x8*)(kr + (((4 + lg) ^ lm7) << 3));
            sv[jf] = __builtin_amdgcn_mfma_f32_16x16x32_bf16(kb0, qa0, sv[jf], 0, 0, 0);
            sv[jf] = __builtin_amdgcn_mfma_f32_16x16x32_bf16(kb1, qa1, sv[jf], 0, 0, 0);
        }
        __builtin_amdgcn_s_setprio(0);

        const bool anym = (__ballot(kmv < 0.f) != 0ULL);
        const bool fastp = (tt >= 1) && (tt <= 7) && !anym;
        if (!fastp) {
            #pragma unroll
            for (int jf = 0; jf < 4; jf++)
                #pragma unroll
                for (int r = 0; r < 4; r++) {
                    const int j = jt0 + jf * 16 + lg * 4 + r;
                    const float km = __shfl(kmv, jf * 16 + lg * 4 + r);
                    const int rel = j - qrow;
                    const bool ok = (rel <= WIN) && (rel >= -WIN) && (km >= 0.f);
                    sv[jf][r] = ok ? sv[jf][r] : -1e9f;
                }
        }

        // ---- online softmax: thread-scalar m,l for q=lm ----
        f32x4 mv = sv[0];
        #pragma unroll
        for (int jf = 1; jf < 4; jf++) {
            mv[0] = fmaxf(mv[0], sv[jf][0]); mv[1] = fmaxf(mv[1], sv[jf][1]);
            mv[2] = fmaxf(mv[2], sv[jf][2]); mv[3] = fmaxf(mv[3], sv[jf][3]);
        }
        float mx = fmaxf(fmaxf(mv[0], mv[1]), fmaxf(mv[2], mv[3]));
        mx = fmaxf(mx, __shfl_xor(mx, 16));
        mx = fmaxf(mx, __shfl_xor(mx, 32));
        const float mnew = fmaxf(mrun, mx);
        const float f = exp2f(mrun - mnew);
        mrun = mnew;

        float p[4][4];
        if (fastp) {
            #pragma unroll
            for (int jf = 0; jf < 4; jf++)
                #pragma unroll
                for (int r = 0; r < 4; r++) p[jf][r] = exp2f(sv[jf][r] - mnew);
        } else {
            #pragma unroll
            for (int jf = 0; jf < 4; jf++)
                #pragma unroll
                for (int r = 0; r < 4; r++)
                    p[jf][r] = sv[jf][r] > -1e8f ? exp2f(sv[jf][r] - mnew) : 0.f;
        }

        float ps = 0.f;
        #pragma unroll
        for (int jf = 0; jf < 4; jf++)
            ps += (p[jf][0] + p[jf][1]) + (p[jf][2] + p[jf][3]);
        ps += __shfl_xor(ps, 16);
        ps += __shfl_xor(ps, 32);
        lrun = lrun * f + ps;

        // ---- pack P -> LDS ----
        u32* prow = (u32*)&Pl[wv][lm][0];
        #pragma unroll
        for (int jf = 0; jf < 4; jf++) {
            u32 lo, hi;
            asm("v_cvt_pk_bf16_f32 %0, %1, %2" : "=v"(lo) : "v"(p[jf][0]), "v"(p[jf][1]));
            asm("v_cvt_pk_bf16_f32 %0, %1, %2" : "=v"(hi) : "v"(p[jf][2]), "v"(p[jf][3]));
            const int c = 2 * jf + (lg >> 1);
            u32x2 val; val[0] = lo; val[1] = hi;
            *(u32x2*)(prow + ((c ^ lm7) << 2) + ((lg & 1) << 1)) = val;
        }
        asm volatile("" ::: "memory");

        po[0] *= f; po[1] *= f; po[2] *= f; po[3] *= f;

        // ---- O^T += V^T . P^T ----
        const u16* pw = &Pl[wv][lm][0];
        const bf16x8 pa0 = *(const bf16x8*)(pw + ((lg ^ lm7) << 3));
        const bf16x8 pa1 = *(const bf16x8*)(pw + (((4 + lg) ^ lm7) << 3));
        __builtin_amdgcn_s_setprio(1);
        #pragma unroll
        for (int df = 0; df < 4; df++) {
            const u16* vr = &Vs[cur][df * 16 + lm][0];
            bf16x8 va0 = *(const bf16x8*)(vr + ((lg ^ lm7) << 3));
            bf16x8 va1 = *(const bf16x8*)(vr + (((4 + lg) ^ lm7) << 3));
            po[df] = __builtin_amdgcn_mfma_f32_16x16x32_bf16(va0, pa0, po[df], 0, 0, 0);
            po[df] = __builtin_amdgcn_mfma_f32_16x16x32_bf16(va1, pa1, po[df], 0, 0, 0);
        }
        __builtin_amdgcn_s_setprio(0);

        if (tt < thi) write_lds(cur ^ 1);
        __syncthreads();
        cur ^= 1;
    }

    const float qm = amask[bS + qrow];
    const float inv = (lrun > 0.f && qm >= 0.f) ? 1.f / lrun : 0.f;
    float* op = out + (bS + qrow) * DM + h * HDIM;
    #pragma unroll
    for (int df = 0; df < 4; df++) {
        f32x4 o = po[df] * inv;
        *(f32x4*)(op + df * 16 + lg * 4) = o;
    }
}

extern "C" void kernel_launch(void* const* d_in, const int* in_sizes, int n_in,
                              void* d_out, int out_size, void* d_ws, size_t ws_size,
                              hipStream_t stream) {
    const float* hs    = (const float*)d_in[0];
    const float* amask = (const float*)d_in[1];
    const float* Wq    = (const float*)d_in[2];
    const float* bq    = (const float*)d_in[3];
    const float* Wk    = (const float*)d_in[4];
    const float* bk    = (const float*)d_in[5];
    const float* Wv    = (const float*)d_in[6];
    const float* bv    = (const float*)d_in[7];

    const size_t nA   = (size_t)BATCH * SEQ * DM;
    const size_t nW   = (size_t)3 * DM * DM;
    const size_t nQKV = (size_t)BATCH * NHEAD * SEQ * HDIM;

    u16* Abf = (u16*)d_ws;
    u16* Wt  = Abf + nA;
    u16* qb  = Wt + nW;
    u16* kb  = qb + nQKV;
    u16* vT  = kb + nQKV;

    prep<<<4800, 256, 0, stream>>>(hs, Abf, Wq, Wk, Wv, Wt);
    qkv_mfma<<<dim3(18, 64), 256, 0, stream>>>(
        Abf, Wt, bq, bk, bv, qb, kb, vT);
    attn_mfma<<<dim3(SEQ / 64, NHEAD, BATCH), 256, 0, stream>>>(
        qb, kb, vT, amask, (float*)d_out);
}